// Round 5
// baseline (1560.185 us; speedup 1.0000x reference)
//
#include <hip/hip_runtime.h>

// Problem constants
#define BDIM 256   // batch
#define TDIM 256   // timesteps
#define IDIM 512   // input dim
#define HDIM 512   // hidden dim
#define G4   2048  // 4*H gate rows

#define HBW64 32768ull                 // ull words per h buffer (256*512/4)
#define SENT  0x7FC07FC07FC07FC0ull    // 4x bf16 NaN: unreachable by valid h
#define TOK1  0xA5A5A5A5A5A5A5A5ull
#define TOK2  0x5A5A5A5A5A5A5A5Aull

typedef __attribute__((ext_vector_type(4))) float f32x4;
typedef __attribute__((ext_vector_type(8))) short short8;     // 8 bf16 MFMA frag
typedef __attribute__((ext_vector_type(8))) unsigned short u16x8;
typedef __attribute__((ext_vector_type(4))) unsigned short u16x4;
typedef unsigned long long ull;

__device__ __forceinline__ unsigned short f2bf(float f) {
  union { float f; unsigned u; } v; v.f = f;
  unsigned r = v.u + 0x7FFFu + ((v.u >> 16) & 1u);   // RNE
  return (unsigned short)(r >> 16);
}
__device__ __forceinline__ float bf2f(unsigned short h) {
  union { unsigned u; float f; } v; v.u = ((unsigned)h) << 16; return v.f;
}
__device__ __forceinline__ float sigmoidf_fast(float x) {
  return 1.0f / (1.0f + __expf(-x));
}
__device__ __forceinline__ float tanhf_fast(float x) {
  float e = __expf(2.0f * x);
  return 1.0f - 2.0f / (e + 1.0f);
}
// async global->LDS 16B DMA (dst = wave-uniform base + lane*16)
__device__ __forceinline__ void gl_lds16(const unsigned short* g, unsigned short* l) {
  __builtin_amdgcn_global_load_lds(
      (const __attribute__((address_space(1))) unsigned int*)g,
      (__attribute__((address_space(3))) unsigned int*)l, 16, 0, 0);
}
// 8B plain store: single global_store_dwordx2 (write-through L1 -> local L2).
__device__ __forceinline__ void store64_l2(ull* p, ull v) {
  asm volatile("global_store_dwordx2 %0, %1, off" :: "v"(p), "v"(v) : "memory");
}
// 8B read AT THE LOCAL L2: real atomic RMW (add 0, sc0 = return old value).
// No sc1 -> executes at this XCD's L2 (the cross-XCD incoherence we EXPLOIT:
// co-located group => same L2). Atomics never hit L1 (kills R8's suspected
// stale-L1), inline asm can't be folded to a load (kills R9's suspected
// atomicrmw-add-0 -> load -> L1 rewrite). Caller batches then waitcnts.
__device__ __forceinline__ void read64_l2_issue(ull* p, ull* dst) {
  asm volatile("global_atomic_add_x2 %0, %1, %2, off sc0"
               : "=&v"(*dst) : "v"(p), "v"(0ull) : "memory");
}
__device__ __forceinline__ void vm_drain() {
  asm volatile("s_waitcnt vmcnt(0)" ::: "memory");
  __builtin_amdgcn_sched_barrier(0);
}
__device__ __forceinline__ ull read64_l2(ull* p) {
  ull v; read64_l2_issue(p, &v); vm_drain(); return v;
}

// xg scatter offset shared by both GEMM epilogues.
__device__ __forceinline__ size_t xg_off(int m, int n) {
  int b = m >> 8, t = m & 255;
  int q = n >> 9, jcol = n & 511;
  return (((size_t)t * 8 + (b >> 5)) * 8 + (jcol >> 6)) * 8192
         + (size_t)q * 2048 + (b & 31) * 64 + (jcol & 63);
}

// ---------------------------------------------------------------------------
// fp32 -> bf16 pre-convert of x (33.5M) and W_ih (1M). 8 elems/thread.
// ---------------------------------------------------------------------------
__global__ void __launch_bounds__(256) convert_bf16(
    const float* __restrict__ x, const float* __restrict__ w,
    unsigned short* __restrict__ xb, unsigned short* __restrict__ wb)
{
  const size_t NX8 = (size_t)BDIM * TDIM * IDIM / 8;   // 4194304
  const size_t NW8 = (size_t)G4 * IDIM / 8;            // 131072
  size_t idx = (size_t)blockIdx.x * 256 + threadIdx.x;
  const float4* sp; u16x8* dp; size_t i;
  if (idx < NX8)      { sp = (const float4*)x; dp = (u16x8*)xb; i = idx; }
  else if (idx < NX8 + NW8) { sp = (const float4*)w; dp = (u16x8*)wb; i = idx - NX8; }
  else return;
  float4 a = sp[i * 2], b = sp[i * 2 + 1];
  u16x8 o = { f2bf(a.x), f2bf(a.y), f2bf(a.z), f2bf(a.w),
              f2bf(b.x), f2bf(b.y), f2bf(b.z), f2bf(b.w) };
  dp[i] = o;
}

// ---------------------------------------------------------------------------
// Arm both h-buffer sets + sync scratch.
//   bufF0/bufS0 <- sentinel; bufF3/bufS3 <- zeros (h_{-1})
//   ftest <- 0, fres <- 0xFFFFFFFF
// Kernel-end writeback makes this visible to lstm_scan on every path.
// ---------------------------------------------------------------------------
__global__ void __launch_bounds__(256) init_bufs(ull* __restrict__ hb,
    ull* __restrict__ ftest, unsigned* __restrict__ fres)
{
  size_t i = (size_t)blockIdx.x * 256 + threadIdx.x;   // 65536 total
  if (i < HBW64)          { hb[i] = SENT; hb[4 * HBW64 + i] = SENT; }
  else if (i < 2 * HBW64) { size_t j = i - HBW64;
                            hb[3 * HBW64 + j] = 0ull; hb[7 * HBW64 + j] = 0ull; }
  if (i < 64) { ftest[i] = 0ull; fres[i] = 0xFFFFFFFFu; }
}

// ---------------------------------------------------------------------------
// Phase 1 (fast): m97-style bf16 GEMM, 128x128 tile, BK=32, global_load_lds 16B.
// ---------------------------------------------------------------------------
__global__ void __launch_bounds__(256, 2) xg_gemm_bf16(
    const unsigned short* __restrict__ Xb, const unsigned short* __restrict__ Wb,
    const float* __restrict__ b_ih, const float* __restrict__ b_hh,
    unsigned short* __restrict__ xg)
{
  __shared__ unsigned short sA[128 * 32];
  __shared__ unsigned short sB[128 * 32];

  const int tid  = threadIdx.x;
  const int lane = tid & 63;
  const int wave = tid >> 6;
  const int l15  = lane & 15;
  const int quad = lane >> 4;
  const int nt = blockIdx.x & 15;
  const int mt = blockIdx.x >> 4;
  const int wm = (wave >> 1) * 64;
  const int wn = (wave & 1) * 64;

  f32x4 acc[4][4];
  #pragma unroll
  for (int i = 0; i < 4; ++i)
    #pragma unroll
    for (int j = 0; j < 4; ++j)
      acc[i][j] = (f32x4){0.f, 0.f, 0.f, 0.f};

  for (int kt = 0; kt < 16; ++kt) {
    #pragma unroll
    for (int i = 0; i < 2; ++i) {
      int c   = wave * 128 + i * 64 + lane;
      int row = c >> 2, cg = c & 3;
      const unsigned short* ga = Xb + (size_t)(mt * 128 + row) * 512 + kt * 32 + cg * 8;
      gl_lds16(ga, sA + (size_t)(wave * 128 + i * 64) * 8);
      const unsigned short* gb = Wb + (size_t)(nt * 128 + row) * 512 + kt * 32 + cg * 8;
      gl_lds16(gb, sB + (size_t)(wave * 128 + i * 64) * 8);
    }
    __syncthreads();

    short8 af[4], bfr[4];
    #pragma unroll
    for (int i = 0; i < 4; ++i) {
      af[i]  = *(const short8*)&sA[(wm + i * 16 + l15) * 32 + quad * 8];
      bfr[i] = *(const short8*)&sB[(wn + i * 16 + l15) * 32 + quad * 8];
    }
    #pragma unroll
    for (int am = 0; am < 4; ++am)
      #pragma unroll
      for (int an = 0; an < 4; ++an)
        acc[am][an] = __builtin_amdgcn_mfma_f32_16x16x32_bf16(
            af[am], bfr[an], acc[am][an], 0, 0, 0);
    __syncthreads();
  }

  float biasv[4];
  #pragma unroll
  for (int an = 0; an < 4; ++an) {
    int n = nt * 128 + wn + an * 16 + l15;
    biasv[an] = b_ih[n] + b_hh[n];
  }
  #pragma unroll
  for (int am = 0; am < 4; ++am)
    #pragma unroll
    for (int reg = 0; reg < 4; ++reg) {
      int m = mt * 128 + wm + am * 16 + quad * 4 + reg;
      #pragma unroll
      for (int an = 0; an < 4; ++an) {
        int n = nt * 128 + wn + an * 16 + l15;
        __builtin_nontemporal_store(f2bf(acc[am][an][reg] + biasv[an]),
                                    &xg[xg_off(m, n)]);
      }
    }
}

// ---------------------------------------------------------------------------
// Phase 1 (fallback, ws too small): fp32-staging GEMM.
// ---------------------------------------------------------------------------
__global__ void __launch_bounds__(256, 2) xg_gemm_f32(
    const float* __restrict__ X, const float* __restrict__ Wih,
    const float* __restrict__ b_ih, const float* __restrict__ b_hh,
    unsigned short* __restrict__ xg)
{
  __shared__ unsigned short sA[128][40];
  __shared__ unsigned short sB[128][40];

  const int tid  = threadIdx.x;
  const int lane = tid & 63;
  const int wave = tid >> 6;
  const int l15  = lane & 15;
  const int quad = lane >> 4;
  const int nt = blockIdx.x;
  const int mt = blockIdx.y;
  const int wm = (wave >> 1) * 64;
  const int wn = (wave & 1) * 64;
  const int r    = tid >> 1;
  const int half = (tid & 1) * 16;

  const float* arow = X   + (size_t)(mt * 128 + r) * 512 + half;
  const float* brow = Wih + (size_t)(nt * 128 + r) * 512 + half;

  f32x4 acc[4][4];
  #pragma unroll
  for (int i = 0; i < 4; ++i)
    #pragma unroll
    for (int j = 0; j < 4; ++j)
      acc[i][j] = (f32x4){0.f, 0.f, 0.f, 0.f};

  for (int kt = 0; kt < 16; ++kt) {
    const float* ap = arow + kt * 32;
    const float* bp = brow + kt * 32;
    #pragma unroll
    for (int i = 0; i < 4; ++i) {
      float4 a = ((const float4*)ap)[i];
      u16x4 av = { f2bf(a.x), f2bf(a.y), f2bf(a.z), f2bf(a.w) };
      *(u16x4*)&sA[r][half + i * 4] = av;
      float4 b = ((const float4*)bp)[i];
      u16x4 bv = { f2bf(b.x), f2bf(b.y), f2bf(b.z), f2bf(b.w) };
      *(u16x4*)&sB[r][half + i * 4] = bv;
    }
    __syncthreads();
    short8 af[4], bfr[4];
    #pragma unroll
    for (int i = 0; i < 4; ++i) {
      af[i]  = *(const short8*)&sA[wm + i * 16 + l15][quad * 8];
      bfr[i] = *(const short8*)&sB[wn + i * 16 + l15][quad * 8];
    }
    #pragma unroll
    for (int am = 0; am < 4; ++am)
      #pragma unroll
      for (int an = 0; an < 4; ++an)
        acc[am][an] = __builtin_amdgcn_mfma_f32_16x16x32_bf16(
            af[am], bfr[an], acc[am][an], 0, 0, 0);
    __syncthreads();
  }

  float biasv[4];
  #pragma unroll
  for (int an = 0; an < 4; ++an) {
    int n = nt * 128 + wn + an * 16 + l15;
    biasv[an] = b_ih[n] + b_hh[n];
  }
  #pragma unroll
  for (int am = 0; am < 4; ++am)
    #pragma unroll
    for (int reg = 0; reg < 4; ++reg) {
      int m = mt * 128 + wm + am * 16 + quad * 4 + reg;
      #pragma unroll
      for (int an = 0; an < 4; ++an) {
        int n = nt * 128 + wn + an * 16 + l15;
        __builtin_nontemporal_store(f2bf(acc[am][an][reg] + biasv[an]),
                                    &xg[xg_off(m, n)]);
      }
    }
}

// ---------------------------------------------------------------------------
// Phase 2: persistent scan — R11: XCD-local L2 exchange, fold-proof read +
// stale-detecting self-test + proven-MALL fallback.
//
//  * bb = blockIdx&7 (== XCD if round-robin dispatch), jw = blockIdx>>3.
//  * Fast path: producer plain-stores (write-through L1 -> shared L2);
//    consumer reads via global_atomic_add_x2(0) sc0 (RMW AT local L2 —
//    never L1-served, never compiler-folded).
//  * Self-test (exact steady-state primitives): round1 publish TOK1 + poll
//    peers; round2 RE-publish TOK2 to the SAME address + re-poll (catches
//    frozen/stale re-reads, the R8/R9 failure). Per-WG result AND-reduced
//    via the proven agent-scope MALL channel -> group-consistent decision.
//    Any failure demotes the group to the R7 MALL protocol on hbS (passed
//    twice, 1489us). Guard-bounded spins -> worst case visible NaN, no hang.
// ---------------------------------------------------------------------------
__global__ void __launch_bounds__(512, 2) lstm_scan(
    const float* __restrict__ Whh, const unsigned short* __restrict__ xg,
    ull* __restrict__ hbF, ull* __restrict__ hbS,
    ull* __restrict__ ftest, unsigned* __restrict__ fres)
{
  __shared__ unsigned short sH[32][520];   // h slice, +8 pad
  __shared__ float sG[32][260];            // gates, +4 pad
  __shared__ int sT, sF;

  const int tid  = threadIdx.x;
  const int lane = tid & 63;
  const int wave = tid >> 6;        // 0..7
  const int l15  = lane & 15;
  const int quad = lane >> 4;
  const int q    = wave >> 1;       // gate (i,f,g,o)
  const int np   = (wave & 1) * 2;  // n-subtile pair
  const int bb = blockIdx.x & 7;    // batch block (== XCD id if RR dispatch)
  const int jw = blockIdx.x >> 3;   // col block 0..7
  const int bbase = bb * 32;
  const int jbase = jw * 64;

  // ---- Self-test round 1: publish TOK1 with the fast-store primitive ------
  if (tid == 0) {
    store64_l2(ftest + blockIdx.x, TOK1);
    asm volatile("s_waitcnt vmcnt(0)" ::: "memory");
  }

  // One-time: W_hh -> 2x16 register B-frags per lane (time filler for peers'
  // token publishes; 128 VGPRs).
  short8 bfrag[2][16];
  #pragma unroll
  for (int n2 = 0; n2 < 2; ++n2) {
    const float* wrow = Whh + (size_t)(q * 512 + jbase + (np + n2) * 16 + l15) * 512;
    #pragma unroll
    for (int ks = 0; ks < 16; ++ks) {
      const float* p = wrow + ks * 32 + quad * 8;
      float4 f0 = ((const float4*)p)[0];
      float4 f1 = ((const float4*)p)[1];
      short8 v;
      v[0] = (short)f2bf(f0.x); v[1] = (short)f2bf(f0.y);
      v[2] = (short)f2bf(f0.z); v[3] = (short)f2bf(f0.w);
      v[4] = (short)f2bf(f1.x); v[5] = (short)f2bf(f1.y);
      v[6] = (short)f2bf(f1.z); v[7] = (short)f2bf(f1.w);
      bfrag[n2][ks] = v;
    }
  }

  // ---- Self-test round 1 poll / round 2 publish+poll ----------------------
  {
    int r1 = 0, r2 = 0;
    if (wave == 0) {
      ull v = 0;
      if (lane < 8) {
        ull* p = ftest + (lane * 8 + bb);      // member (bb, jw=lane)
        for (int g = 0; g < (1 << 13); ++g) {
          v = read64_l2(p);
          if (v == TOK1 || v == TOK2) break;   // peer may already be in rnd2
          __builtin_amdgcn_s_sleep(2);
        }
      }
      int ok = (lane >= 8) || (((v == TOK1) | (v == TOK2)) != 0);
      ull m = __ballot(ok);
      if (lane == 0) sT = ((m & 0xFFull) == 0xFFull) ? 1 : 0;
    }
    __syncthreads();
    r1 = sT;
    // Round 2: re-publish to the SAME address, re-poll the SAME addresses.
    if (r1 && tid == 0) {
      store64_l2(ftest + blockIdx.x, TOK2);
      asm volatile("s_waitcnt vmcnt(0)" ::: "memory");
    }
    __syncthreads();
    if (r1) {
      if (wave == 0) {
        ull v = 0;
        if (lane < 8) {
          ull* p = ftest + (lane * 8 + bb);
          for (int g = 0; g < (1 << 13); ++g) {
            v = read64_l2(p);
            if (v == TOK2) break;
            __builtin_amdgcn_s_sleep(2);
          }
        }
        int ok = (lane >= 8) || (v == TOK2);
        ull m = __ballot(ok);
        if (lane == 0) sT = ((m & 0xFFull) == 0xFFull) ? 1 : 0;
      }
      __syncthreads();
      r2 = sT;
    }
    // ---- Group-consistent AND via the proven MALL channel -----------------
    if (tid == 0)
      __hip_atomic_store(fres + blockIdx.x, (unsigned)(r1 && r2),
                         __ATOMIC_RELAXED, __HIP_MEMORY_SCOPE_AGENT);
    if (wave == 0) {
      unsigned v = 0xFFFFFFFFu;
      if (lane < 8) {
        const unsigned* p = fres + (lane * 8 + bb);
        for (int g = 0; g < (1 << 18); ++g) {
          v = __hip_atomic_load(p, __ATOMIC_RELAXED, __HIP_MEMORY_SCOPE_AGENT);
          if (v != 0xFFFFFFFFu) break;
          __builtin_amdgcn_s_sleep(2);
        }
      }
      int ok = (lane >= 8) || (v == 1u);
      ull m = __ballot(ok);
      if (lane == 0) sF = ((m & 0xFFull) == 0xFFull) ? 1 : 0;
    }
    __syncthreads();
  }
  const int fastok = sF;

  const int r  = tid >> 4;          // gate-math row 0..31
  const int j0 = (tid & 15) * 4;    // gate-math col group
  float c[4] = {0.f, 0.f, 0.f, 0.f};

  // The one 8B h-word this thread owns (writes every step, wipes one ahead).
  const size_t myw = (size_t)(bbase + r) * 128 + (size_t)((jbase + j0) >> 2);

  for (int t = 0; t < TDIM; ++t) {
    const size_t sb = (size_t)((t + 3) & 3) * HBW64;   // h_{t-1}
    const size_t db = (size_t)(t & 3) * HBW64;         // h_t

    // Re-arm own t+1 word early (ordered before the publish by vmcnt(0)).
    if (t < TDIM - 2) {
      const size_t wb = (size_t)((t + 1) & 3) * HBW64;
      if (fastok) store64_l2(hbF + wb + myw, SENT);
      else        __hip_atomic_store(hbS + wb + myw, SENT, __ATOMIC_RELAXED,
                                     __HIP_MEMORY_SCOPE_AGENT);
    }

    // xg loads for step t (nt: streaming; in flight across the poll).
    const unsigned short* xgb = xg + (((size_t)t * 8 + bb) * 8 + jw) * 8192;
    ull xv64[4];
    #pragma unroll
    for (int qq = 0; qq < 4; ++qq)
      xv64[qq] = __builtin_nontemporal_load(
          (const ull*)(xgb + qq * 2048 + r * 64 + j0));

    // ---- Poll-stage h_{t-1}: 8 words/thread, sentinel-tagged data ---------
    ull hv[8];
    if (fastok) {
      ull* sp = hbF + sb + (size_t)bbase * 128 + tid;
      // Batch-issue in 2 groups of 4 (VGPR pressure), then drain.
      #pragma unroll
      for (int i = 0; i < 4; ++i) read64_l2_issue(sp + (size_t)i * 512, &hv[i]);
      vm_drain();
      #pragma unroll
      for (int i = 4; i < 8; ++i) read64_l2_issue(sp + (size_t)i * 512, &hv[i]);
      vm_drain();
      for (int guard = 0; guard < (1 << 18); ++guard) {
        int bad = 0;
        #pragma unroll
        for (int i = 0; i < 8; ++i) bad |= (int)(hv[i] == SENT) << i;
        if (!bad) break;
        __builtin_amdgcn_s_sleep(1);
        #pragma unroll
        for (int i = 0; i < 8; ++i)
          if (bad & (1 << i)) read64_l2_issue(sp + (size_t)i * 512, &hv[i]);
        vm_drain();
      }
    } else {
      const ull* sp = hbS + sb + (size_t)bbase * 128 + tid;
      #pragma unroll
      for (int i = 0; i < 8; ++i)
        hv[i] = __hip_atomic_load(sp + (size_t)i * 512, __ATOMIC_RELAXED,
                                  __HIP_MEMORY_SCOPE_AGENT);
      for (int guard = 0; guard < (1 << 18); ++guard) {
        int bad = 0;
        #pragma unroll
        for (int i = 0; i < 8; ++i) bad |= (int)(hv[i] == SENT) << i;
        if (!bad) break;
        __builtin_amdgcn_s_sleep(1);
        #pragma unroll
        for (int i = 0; i < 8; ++i)
          if (bad & (1 << i))
            hv[i] = __hip_atomic_load(sp + (size_t)i * 512, __ATOMIC_RELAXED,
                                      __HIP_MEMORY_SCOPE_AGENT);
      }
    }
    #pragma unroll
    for (int i = 0; i < 8; ++i) {
      int idx = i * 512 + tid;
      *(ull*)&sH[idx >> 7][(idx & 127) * 4] = hv[i];
    }
    __syncthreads();   // (b) sH staged

    // G-tile MFMA: 2 m-subtiles x 2 n-subtiles, K=512.
    f32x4 acc[2][2];
    acc[0][0] = acc[0][1] = acc[1][0] = acc[1][1] = (f32x4){0.f,0.f,0.f,0.f};
    #pragma unroll
    for (int ks = 0; ks < 16; ++ks) {
      int koff = ks * 32 + quad * 8;
      short8 a0 = *(const short8*)&sH[l15][koff];
      short8 a1 = *(const short8*)&sH[16 + l15][koff];
      acc[0][0] = __builtin_amdgcn_mfma_f32_16x16x32_bf16(a0, bfrag[0][ks], acc[0][0], 0, 0, 0);
      acc[1][0] = __builtin_amdgcn_mfma_f32_16x16x32_bf16(a1, bfrag[0][ks], acc[1][0], 0, 0, 0);
      acc[0][1] = __builtin_amdgcn_mfma_f32_16x16x32_bf16(a0, bfrag[1][ks], acc[0][1], 0, 0, 0);
      acc[1][1] = __builtin_amdgcn_mfma_f32_16x16x32_bf16(a1, bfrag[1][ks], acc[1][1], 0, 0, 0);
    }
    #pragma unroll
    for (int m = 0; m < 2; ++m)
      #pragma unroll
      for (int n2 = 0; n2 < 2; ++n2) {
        int col = q * 64 + (np + n2) * 16 + l15;
        #pragma unroll
        for (int rr = 0; rr < 4; ++rr)
          sG[m * 16 + quad * 4 + rr][col] = acc[m][n2][rr];
      }
    __syncthreads();   // (c) sG ready; also fences sH reads vs next staging

    // Gate math: 4 cells (r, j0..j0+3).
    {
      float4 GI = *(const float4*)&sG[r][j0];
      float4 GF = *(const float4*)&sG[r][64 + j0];
      float4 GG = *(const float4*)&sG[r][128 + j0];
      float4 GO = *(const float4*)&sG[r][192 + j0];
      u16x4 xi  = __builtin_bit_cast(u16x4, xv64[0]);
      u16x4 xf  = __builtin_bit_cast(u16x4, xv64[1]);
      u16x4 xgv = __builtin_bit_cast(u16x4, xv64[2]);
      u16x4 xo  = __builtin_bit_cast(u16x4, xv64[3]);
      float gi[4] = {GI.x, GI.y, GI.z, GI.w};
      float gf[4] = {GF.x, GF.y, GF.z, GF.w};
      float gg[4] = {GG.x, GG.y, GG.z, GG.w};
      float go[4] = {GO.x, GO.y, GO.z, GO.w};
      float h4[4];
      #pragma unroll
      for (int k = 0; k < 4; ++k) {
        float vi = sigmoidf_fast(gi[k] + bf2f(xi[k]));
        float vf = sigmoidf_fast(gf[k] + bf2f(xf[k]));
        float vg = tanhf_fast   (gg[k] + bf2f(xgv[k]));
        float vo = sigmoidf_fast(go[k] + bf2f(xo[k]));
        c[k] = vf * c[k] + vi * vg;
        h4[k] = vo * tanhf_fast(c[k]);
      }
      ull hvout = (ull)f2bf(h4[0])
                | ((ull)f2bf(h4[1]) << 16)
                | ((ull)f2bf(h4[2]) << 32)
                | ((ull)f2bf(h4[3]) << 48);
      // Drain: wipe (and everything else) committed before h_t observable.
      vm_drain();
      // hbF always gets the data (fast sync + head_kernel source);
      // hbS only on the MALL path.
      store64_l2(hbF + db + myw, hvout);
      if (!fastok)
        __hip_atomic_store(hbS + db + myw, hvout, __ATOMIC_RELAXED,
                           __HIP_MEMORY_SCOPE_AGENT);
    }
    // No trailing barrier: next (b) fences sG reads; (c) fenced sH.
  }
}

// ---------------------------------------------------------------------------
// Head: out[b] = h_last[b,:] . fc_w + fc_b
// ---------------------------------------------------------------------------
__global__ void head_kernel(const unsigned short* __restrict__ h,
                            const float* __restrict__ fc_w,
                            const float* __restrict__ fc_b,
                            float* __restrict__ out)
{
  const int b = blockIdx.x;
  const int lane = threadIdx.x;
  const unsigned short* hr = h + (size_t)b * 512;
  float s = 0.f;
  #pragma unroll
  for (int i = 0; i < 8; ++i) {
    int idx = lane + i * 64;
    s += bf2f(hr[idx]) * fc_w[idx];
  }
  #pragma unroll
  for (int off = 32; off > 0; off >>= 1) s += __shfl_down(s, off);
  if (lane == 0) out[b] = s + fc_b[0];
}

// ---------------------------------------------------------------------------
extern "C" void kernel_launch(void* const* d_in, const int* in_sizes, int n_in,
                              void* d_out, int out_size, void* d_ws, size_t ws_size,
                              hipStream_t stream) {
  const float* x    = (const float*)d_in[0];
  const float* W_ih = (const float*)d_in[1];
  const float* W_hh = (const float*)d_in[2];
  const float* b_ih = (const float*)d_in[3];
  const float* b_hh = (const float*)d_in[4];
  const float* fc_w = (const float*)d_in[5];
  const float* fc_b = (const float*)d_in[6];
  float* out = (float*)d_out;

  // Workspace layout:
  //   [0, XG)                xg bf16 (scan-blocked)
  //   [XG, XG+1MB)           hbF: 4 rotating fast (L2) h buffers
  //   [XG+1MB, XG+2MB)       hbS: 4 rotating slow (MALL) h buffers
  //   [XG+2MB, ...)          ftest[64] (512B) | fres[64] (256B)
  //   These alias xb (64MB, dead after xg_gemm_bf16); init_bufs runs after
  //   the GEMM, so the alias is safe.
  const size_t XG  = (size_t)BDIM * TDIM * G4 * 2;     // 268435456
  char* ws = (char*)d_ws;
  unsigned short* xg = (unsigned short*)ws;
  ull* hbF = (ull*)(ws + XG);
  ull* hbS = hbF + 4 * HBW64;
  char* aux = ws + XG + 8 * HBW64 * 8;                 // +2MB
  ull*      ftest = (ull*)aux;
  unsigned* fres  = (unsigned*)(aux + 512);
  const size_t XB_OFF = XG;
  const size_t WB_OFF = XG + (size_t)BDIM * TDIM * IDIM * 2;  // +64MB
  const size_t NEED   = WB_OFF + (size_t)G4 * IDIM * 2;       // +2MB

  if (ws_size >= NEED) {
    unsigned short* xb = (unsigned short*)(ws + XB_OFF);
    unsigned short* wb = (unsigned short*)(ws + WB_OFF);
    convert_bf16<<<16896, 256, 0, stream>>>(x, W_ih, xb, wb);
    xg_gemm_bf16<<<8192, 256, 0, stream>>>(xb, wb, b_ih, b_hh, xg);
  } else {
    xg_gemm_f32<<<dim3(16, 512), 256, 0, stream>>>(x, W_ih, b_ih, b_hh, xg);
  }
  // Arm both buffer sets + sync scratch. MUST come after the GEMM (alias xb).
  init_bufs<<<256, 256, 0, stream>>>(hbF, ftest, fres);
  lstm_scan<<<64, 512, 0, stream>>>(W_hh, xg, hbF, hbS, ftest, fres);
  // h_255 lives in buf[255 & 3] = buf3 of the fast set (always written).
  head_kernel<<<BDIM, 64, 0, stream>>>((const unsigned short*)(hbF + 3 * HBW64),
                                       fc_w, fc_b, out);
}